// Round 20
// baseline (357.473 us; speedup 1.0000x reference)
//
#include <hip/hip_runtime.h>
#include <hip/hip_bf16.h>

#define TT 1024
#define HH 2048
#define EE 16
#define KK 4
#define II 1408
#define IIS 2816
#define GU_MAXT 448
#define DN_MAXT 320
#define TRD_WD (32 * 22 * 16)   // wd transpose tiles (11264)
#define TRD_SD (32 * 44)        // sd transpose tiles (1408)
#define TRD_BLK8 ((TRD_WD + TRD_SD) / 8)   // 1584 trailing blocks, 8 tiles each
// route+tr fused dispatch tile counts
#define TR_GU (22 * 32 * 32)    // wg+wu tiles (22528)
#define TR_SGU (44 * 32 * 2)    // sg+su tiles (2816)
#define TR_BLK8 ((TR_GU + TR_SGU) / 8)   // 3168 transpose blocks, 8 tiles each

typedef __bf16 bf16x8 __attribute__((ext_vector_type(8)));
typedef float f32x4 __attribute__((ext_vector_type(4)));

__device__ __forceinline__ f32x4 mfma16(bf16x8 a, bf16x8 b, f32x4 c) {
  return __builtin_amdgcn_mfma_f32_16x16x32_bf16(a, b, c, 0, 0, 0);
}

__device__ __forceinline__ void gl_lds16(const void* g, void* l) {
  __builtin_amdgcn_global_load_lds(
      (const __attribute__((address_space(1))) void*)g,
      (__attribute__((address_space(3))) void*)l, 16, 0, 0);
}

__device__ __forceinline__ unsigned int pk2(float a, float b) {
  unsigned short lo = __builtin_bit_cast(unsigned short, (__bf16)a);
  unsigned short hi = __builtin_bit_cast(unsigned short, (__bf16)b);
  return (unsigned int)lo | ((unsigned int)hi << 16);
}

__device__ __forceinline__ uint4 pack8(const float* f) {
  uint4 r;
  r.x = pk2(f[0], f[1]);
  r.y = pk2(f[2], f[3]);
  r.z = pk2(f[4], f[5]);
  r.w = pk2(f[6], f[7]);
  return r;
}

__device__ __forceinline__ float bf2f(unsigned short u) {
  return __builtin_bit_cast(float, (unsigned int)u << 16);
}

// ------- fused: routing (blocks < TT) + PIPELINED wg/wu/sg/su transpose -----
// Transpose blocks: 8 homogeneous tiles each (all group strides divisible by
// 8, so src/dst/z are loop-invariant); register dbuf keeps the next tile's
// 4 float4 loads in flight across barrier+store of the current tile.
__global__ __launch_bounds__(256)
void k_route_tr(const float* __restrict__ x, const float* __restrict__ gw,
                const float* __restrict__ gb,
                int* __restrict__ topk_idx, float* __restrict__ wvec,
                __bf16* __restrict__ xb,
                const float* __restrict__ wg, __bf16* __restrict__ wgT,
                const float* __restrict__ wu, __bf16* __restrict__ wuT,
                const float* __restrict__ sg, __bf16* __restrict__ sgT,
                const float* __restrict__ su, __bf16* __restrict__ suT)
{
  __shared__ float tsm[64][65];
  const int bid = blockIdx.x;
  const int tid = threadIdx.x;
  if (bid >= TT) {
    const int tb = bid - TT;
    const int t0 = tb * 8;
    const float* src; __bf16* dst; int C_, zb;
    int xs[8], ys[8];
    if (t0 < TR_GU) {
      int z = t0 / (22 * 32);
      C_ = II;
      if (z < EE) { src = wg; dst = wgT; zb = z; }
      else        { src = wu; dst = wuT; zb = z - EE; }
#pragma unroll
      for (int j = 0; j < 8; ++j) {
        int tt = t0 + j;
        xs[j] = tt % 22; ys[j] = (tt / 22) & 31;
      }
    } else {
      int t2 = t0 - TR_GU;
      int z = t2 / (44 * 32);
      C_ = IIS;
      if (z == 0) { src = sg; dst = sgT; } else { src = su; dst = suT; }
      zb = 0;
#pragma unroll
      for (int j = 0; j < 8; ++j) {
        int tt = t2 + j;
        xs[j] = tt % 44; ys[j] = (tt / 44) & 31;
      }
    }
    const size_t mb = (size_t)zb * HH * C_;
    const int r_ld = tid >> 4, q_ld = tid & 15;
    const int n_st = tid >> 3, q8_st = tid & 7;

    float4 A[4], B[4];
#define RT_LOAD(V, j)                                                        \
    { _Pragma("unroll")                                                      \
      for (int it = 0; it < 4; ++it)                                         \
        V[it] = *reinterpret_cast<const float4*>(src + mb                    \
            + (size_t)(ys[j] * 64 + it * 16 + r_ld) * C_                     \
            + xs[j] * 64 + q_ld * 4); }

    RT_LOAD(A, 0)
#pragma unroll
    for (int j = 0; j < 8; ++j) {
#pragma unroll
      for (int it = 0; it < 4; ++it) {
        int r = it * 16 + r_ld;
        tsm[r][q_ld * 4 + 0] = A[it].x; tsm[r][q_ld * 4 + 1] = A[it].y;
        tsm[r][q_ld * 4 + 2] = A[it].z; tsm[r][q_ld * 4 + 3] = A[it].w;
      }
      if (j < 7) { RT_LOAD(B, j + 1) }     // next tile's loads in flight
      __syncthreads();
#pragma unroll
      for (int it = 0; it < 2; ++it) {
        int n = it * 32 + n_st;
        float f[8];
#pragma unroll
        for (int jj = 0; jj < 8; ++jj) f[jj] = tsm[q8_st * 8 + jj][n];
        *reinterpret_cast<uint4*>(dst + mb
            + (size_t)(xs[j] * 64 + n) * HH + ys[j] * 64 + q8_st * 8) = pack8(f);
      }
      __syncthreads();
      if (j < 7) {
#pragma unroll
        for (int it = 0; it < 4; ++it) A[it] = B[it];
      }
    }
#undef RT_LOAD
    return;
  }
  // ---------------- routing body ----------------
  const int t = bid;
  float a[EE];
#pragma unroll
  for (int e = 0; e < EE; ++e) a[e] = 0.f;
  for (int h = tid; h < HH; h += 256) {
    float xv = x[(size_t)t * HH + h];
    xb[(size_t)t * HH + h] = (__bf16)xv;
#pragma unroll
    for (int e = 0; e < EE; ++e) a[e] += xv * gw[e * HH + h];
  }
  const int lane = tid & 63, wv = tid >> 6;
#pragma unroll
  for (int e = 0; e < EE; ++e) {
    float v = a[e];
#pragma unroll
    for (int off = 32; off > 0; off >>= 1) v += __shfl_xor(v, off);
    if (lane == 0) tsm[wv][e] = v;
  }
  __syncthreads();
  if (tid == 0) {
    float sc[EE], sb[EE];
    for (int e = 0; e < EE; ++e) {
      float lg = tsm[0][e] + tsm[1][e] + tsm[2][e] + tsm[3][e];
      sc[e] = 1.f / (1.f + expf(-lg));
      sb[e] = sc[e] + gb[e];
    }
    float gsc[4];
    for (int g = 0; g < 4; ++g) {
      float m1 = -1e30f, m2 = -1e30f;
      for (int j = 0; j < 4; ++j) {
        float v = sb[g * 4 + j];
        if (v > m1) { m2 = m1; m1 = v; } else if (v > m2) { m2 = v; }
      }
      gsc[g] = m1 + m2;
    }
    int g1 = 0; float b1 = gsc[0];
    for (int g = 1; g < 4; ++g) if (gsc[g] > b1) { b1 = gsc[g]; g1 = g; }
    int g2 = 0; float b2 = -1e30f;
    for (int g = 0; g < 4; ++g) if (g != g1 && gsc[g] > b2) { b2 = gsc[g]; g2 = g; }
    bool used[EE];
    for (int e = 0; e < EE; ++e) used[e] = !(((e >> 2) == g1) || ((e >> 2) == g2));
    int sel[KK]; float sw[KK]; float ssum = 0.f;
    for (int j = 0; j < KK; ++j) {
      float best = -1e30f; int bi = 0;
      for (int e = 0; e < EE; ++e)
        if (!used[e] && sb[e] > best) { best = sb[e]; bi = e; }
      used[bi] = true; sel[j] = bi; sw[j] = sc[bi]; ssum += sc[bi];
    }
    float s = 2.5f / (ssum + 1e-20f);
    for (int j = 0; j < KK; ++j) {
      topk_idx[t * KK + j] = sel[j];
      wvec[t * KK + j] = sw[j] * s;
    }
  }
}

// ------ deterministic expert lists + compacted tile tables -------
// gu: BM=256 x BN=128, order (e, nt, rt)
// dn: BM=256 x BN=256, order (e, rt, nt); SHARED expert split into two
//     K-halves (e = EE -> k half 0, e = EE+1 -> k half 1), 22 steps each.
__global__ __launch_bounds__(1024)
void k_lists(const int* __restrict__ topk_idx,
             int* __restrict__ counts, int* __restrict__ offs,
             int* __restrict__ list, int* __restrict__ row_of,
             int* __restrict__ hdr, int* __restrict__ gu_tab,
             int* __restrict__ dn_tab)
{
  const int t = threadIdx.x;
  const int lane = t & 63, wv = t >> 6;
  const int e0 = topk_idx[t * 4 + 0], e1 = topk_idx[t * 4 + 1],
            e2 = topk_idx[t * 4 + 2], e3 = topk_idx[t * 4 + 3];
  __shared__ int wtot[16];
  __shared__ int cnt[EE];
  __shared__ int offsh[EE + 1];
  __shared__ int rtn[EE], gpre[EE + 1], dpre[EE + 1];
  int p0 = 0, p1 = 0, p2 = 0, p3 = 0;
  for (int e = 0; e < EE; ++e) {
    bool f = (e0 == e) || (e1 == e) || (e2 == e) || (e3 == e);
    unsigned long long b = __ballot(f);
    if (lane == 0) wtot[wv] = __popcll(b);
    __syncthreads();
    int wo = 0;
    for (int w2 = 0; w2 < wv; ++w2) wo += wtot[w2];
    if (f) {
      int pos = wo + __popcll(b & ((1ull << lane) - 1ull));
      list[e * TT + pos] = t;
      if (e0 == e) p0 = pos; else if (e1 == e) p1 = pos;
      else if (e2 == e) p2 = pos; else p3 = pos;
    }
    if (t == 0) {
      int tot = 0;
      for (int w2 = 0; w2 < 16; ++w2) tot += wtot[w2];
      cnt[e] = tot;
    }
    __syncthreads();
  }
  if (t == 0) {
    offsh[0] = 0;
    for (int e = 0; e < EE; ++e) offsh[e + 1] = offsh[e] + cnt[e];
    for (int e = 0; e < EE; ++e) { counts[e] = cnt[e]; offs[e] = offsh[e]; }
    gpre[0] = 0; dpre[0] = 0;
    for (int e = 0; e < EE; ++e) {
      int rr = (cnt[e] + 255) >> 8;           // ceil(cnt/256)
      rtn[e] = rr;
      gpre[e + 1] = gpre[e] + rr * (II / 128);
      dpre[e + 1] = dpre[e] + rr * (HH / 256);
    }
    hdr[0] = gpre[EE] + 4 * (IIS / 128);      // gu shared: 4 row-tiles of 256
    hdr[1] = dpre[EE] + 2 * 4 * (HH / 256);   // dn shared: 2 K-halves x 4 rt x 8 nt
  }
  __syncthreads();
  row_of[t * 4 + 0] = offsh[e0] + p0;
  row_of[t * 4 + 1] = offsh[e1] + p1;
  row_of[t * 4 + 2] = offsh[e2] + p2;
  row_of[t * 4 + 3] = offsh[e3] + p3;
  if (t < EE) {
    int rr = rtn[t];
    int p = gpre[t];
    for (int nt = 0; nt < II / 128; ++nt)
      for (int rt = 0; rt < rr; ++rt) gu_tab[p++] = (t << 16) | (rt << 8) | nt;
    p = dpre[t];
    for (int rt = 0; rt < rr; ++rt)
      for (int nt = 0; nt < HH / 256; ++nt) dn_tab[p++] = (t << 16) | (rt << 8) | nt;
  } else if (t == EE) {
    int p = gpre[EE];
    for (int nt = 0; nt < IIS / 128; ++nt)
      for (int rt = 0; rt < 4; ++rt) gu_tab[p++] = (EE << 16) | (rt << 8) | nt;
    p = dpre[EE];
    for (int kh = 0; kh < 2; ++kh)
      for (int rt = 0; rt < 4; ++rt)
        for (int nt = 0; nt < HH / 256; ++nt)
          dn_tab[p++] = ((EE + kh) << 16) | (rt << 8) | nt;
  }
}

// ---- fused: gate/up GEMM (BM=256, dbuf, counted-vmcnt) + wd/sd transpose ----
// Trailing transpose blocks: 8 tiles each, software-pipelined (reg dbuf).
struct GU_SM {
  uint4 As[2][2048];
  uint4 Bgs[2][1024];
  uint4 Bus[2][1024];
  int toks[256];
};
union FSM { GU_SM g; float t[64][65]; };

__global__ __launch_bounds__(512)
void k_gu_trd(const __bf16* __restrict__ xb,
              const __bf16* __restrict__ wgT, const __bf16* __restrict__ wuT,
              const __bf16* __restrict__ sgT, const __bf16* __restrict__ suT,
              const int* __restrict__ counts, const int* __restrict__ offs,
              const int* __restrict__ list, const int* __restrict__ hdr,
              const int* __restrict__ gu_tab,
              __bf16* __restrict__ a_buf, __bf16* __restrict__ s_buf,
              const float* __restrict__ wd, __bf16* __restrict__ wdT,
              const float* __restrict__ sd, __bf16* __restrict__ sdT)
{
  __shared__ FSM sm;
  const int bid = blockIdx.x;
  if (bid >= GU_MAXT) {
    // ---- pipelined trailing transpose: 8 homogeneous tiles per block ----
    const int tb = bid - GU_MAXT;
    const int tid2 = threadIdx.x;
    const bool isWd = (tb * 8) < TRD_WD;       // TRD_WD % 8 == 0
    const float* src = isWd ? wd : sd;
    __bf16* dst = isWd ? wdT : sdT;
    const int R = isWd ? II : IIS;
    const int t0 = isWd ? tb * 8 : tb * 8 - TRD_WD;
    const int r_ld = tid2 >> 4, q_ld = tid2 & 15;   // rows r_ld, r_ld+32
    const int n_st = tid2 >> 3, q8_st = tid2 & 7;

    int xs[8], ys[8], zs[8];
#pragma unroll
    for (int j = 0; j < 8; ++j) {
      int tile = t0 + j;
      xs[j] = tile & 31;
      ys[j] = isWd ? ((tile >> 5) % 22) : (tile >> 5);
      zs[j] = isWd ? (tile / (32 * 22)) : 0;
    }

    float4 A0, A1, B0, B1;
#define TR_LOAD(Va, Vb, j)                                                   \
    { const float* p_ = src + (size_t)zs[j] * R * HH                         \
          + (size_t)(ys[j] * 64 + r_ld) * HH + xs[j] * 64 + q_ld * 4;        \
      Va = *reinterpret_cast<const float4*>(p_);                             \
      Vb = *reinterpret_cast<const float4*>(p_ + (size_t)32 * HH); }

    TR_LOAD(A0, A1, 0)
#pragma unroll
    for (int j = 0; j < 8; ++j) {
      sm.t[r_ld][q_ld * 4 + 0] = A0.x; sm.t[r_ld][q_ld * 4 + 1] = A0.y;
      sm.t[r_ld][q_ld * 4 + 2] = A0.z; sm.t[r_ld][q_ld * 4 + 3] = A0.w;
      sm.t[r_ld + 32][q_ld * 4 + 0] = A1.x; sm.t[r_ld + 32][q_ld * 4 + 1] = A1.y;
      sm.t[r_ld + 32][q_ld * 4 + 2] = A1.z; sm.t[r_ld + 32][q_ld * 4 + 3] = A1.w;
      if (j < 7) { TR_LOAD(B0, B1, j + 1) }    // next tile in flight
      __syncthreads();
      {
        float f[8];
#pragma unroll
        for (int jj = 0; jj < 8; ++jj) f[jj] = sm.t[q8_st * 8 + jj][n_st];
        *reinterpret_cast<uint4*>(dst + (size_t)zs[j] * R * HH
            + (size_t)(xs[j] * 64 + n_st) * R + ys[j] * 64 + q8_st * 8) = pack8(f);
      }
      __syncthreads();
      if (j < 7) { A0 = B0; A1 = B1; }
    }
#undef TR_LOAD
    return;
  }
  const int nwg = hdr[0];
  if (bid >= nwg) return;
  const int qq = nwg >> 3, r8 = nwg & 7, xcd = bid & 7;
  const int wgid = (xcd < r8 ? xcd * (qq + 1) : r8 * (qq + 1) + (xcd - r8) * qq)
                   + (bid >> 3);
  const int ent = gu_tab[wgid];
  const int e = ent >> 16, rt = (ent >> 8) & 255, nt = ent & 255;
  const bool SH = (e == EE);
  const int Nt = SH ? IIS : II;
  const int n0 = nt * 128, row0 = rt * 256;
  const int n_rows = SH ? TT : counts[e];
  if (row0 >= n_rows) return;
  const int base = SH ? 0 : offs[e];
  const __bf16* Bg = SH ? sgT : wgT + (size_t)e * II * HH;
  const __bf16* Bu = SH ? suT : wuT + (size_t)e * II * HH;
  __bf16* outp = SH ? s_buf : a_buf;

  const int tid = threadIdx.x;
  const int lane = tid & 63, w = tid >> 6;
  if (tid < 256) {
    int rr = row0 + tid;
    sm.g.toks[tid] = SH ? rr : list[e * TT + (rr < n_rows ? rr : row0)];
  }
  __syncthreads();

  const __bf16 *pA[4], *pBg[2], *pBu[2];
#pragma unroll
  for (int i = 0; i < 4; ++i) {
    int s = w * 256 + i * 64 + lane;
    int r = s >> 3, k8 = (s & 7) ^ (r & 7);
    pA[i] = xb + (size_t)sm.g.toks[r] * HH + k8 * 8;
  }
#pragma unroll
  for (int i = 0; i < 2; ++i) {
    int s = w * 128 + i * 64 + lane;
    int r = s >> 3, k8 = (s & 7) ^ (r & 7);
    pBg[i] = Bg + (size_t)(n0 + r) * HH + k8 * 8;
    pBu[i] = Bu + (size_t)(n0 + r) * HH + k8 * 8;
  }

  f32x4 accg[4][4], accu[4][4];
  const f32x4 fz = {0.f, 0.f, 0.f, 0.f};
#pragma unroll
  for (int m = 0; m < 4; ++m)
#pragma unroll
    for (int n = 0; n < 4; ++n) { accg[m][n] = fz; accu[m][n] = fz; }

  const int wm = w >> 1, wn = w & 1;
  const int lr = lane & 15, l16 = lane >> 4;

#define GU_STAGE(b, k0)                                            \
  {                                                                \
    _Pragma("unroll")                                              \
    for (int i = 0; i < 4; ++i)                                    \
      gl_lds16(pA[i] + (k0), &sm.g.As[b][w * 256 + i * 64]);       \
    _Pragma("unroll")                                              \
    for (int i = 0; i < 2; ++i) {                                  \
      gl_lds16(pBg[i] + (k0), &sm.g.Bgs[b][w * 128 + i * 64]);     \
      gl_lds16(pBu[i] + (k0), &sm.g.Bus[b][w * 128 + i * 64]);     \
    }                                                              \
  }

  GU_STAGE(0, 0);
  int cur = 0;
  for (int t = 0; t < HH / 64; ++t) {
    if (t + 1 < HH / 64) {
      GU_STAGE(cur ^ 1, (t + 1) * 64);
      asm volatile("s_waitcnt vmcnt(8)" ::: "memory");
    } else {
      asm volatile("s_waitcnt vmcnt(0)" ::: "memory");
    }
    __builtin_amdgcn_s_barrier();
#pragma unroll
    for (int ks = 0; ks < 2; ++ks) {
      const int k8r = ks * 4 + l16;
      bf16x8 af[4], bg[4], bu[4];
#pragma unroll
      for (int m = 0; m < 4; ++m) {
        int rw = wm * 64 + m * 16 + lr;
        af[m] = *reinterpret_cast<const bf16x8*>(
            &sm.g.As[cur][rw * 8 + (k8r ^ (rw & 7))]);
      }
#pragma unroll
      for (int n = 0; n < 4; ++n) {
        int cn = wn * 64 + n * 16 + lr;
        bg[n] = *reinterpret_cast<const bf16x8*>(
            &sm.g.Bgs[cur][cn * 8 + (k8r ^ (cn & 7))]);
        bu[n] = *reinterpret_cast<const bf16x8*>(
            &sm.g.Bus[cur][cn * 8 + (k8r ^ (cn & 7))]);
      }
#pragma unroll
      for (int m = 0; m < 4; ++m)
#pragma unroll
        for (int n = 0; n < 4; ++n) {
          accg[m][n] = mfma16(af[m], bg[n], accg[m][n]);
          accu[m][n] = mfma16(af[m], bu[n], accu[m][n]);
        }
    }
    __builtin_amdgcn_s_barrier();
    cur ^= 1;
  }
#pragma unroll
  for (int m = 0; m < 4; ++m)
#pragma unroll
    for (int n = 0; n < 4; ++n)
#pragma unroll
      for (int q = 0; q < 4; ++q) {
        int rloc = wm * 64 + m * 16 + l16 * 4 + q;
        if (row0 + rloc >= n_rows) continue;
        int cloc = wn * 64 + n * 16 + lr;
        float g = accg[m][n][q], u = accu[m][n][q];
        float sv = g / (1.f + __expf(-g)) * u;
        outp[(size_t)(base + row0 + rloc) * Nt + (n0 + cloc)] = (__bf16)sv;
      }
#undef GU_STAGE
}

// ---- down GEMM: BM=256, BN=256, BK=64, counted-vmcnt; shared K-split ----
__global__ __launch_bounds__(512)
void k_down5(const __bf16* __restrict__ a_buf, const __bf16* __restrict__ s_buf,
             const __bf16* __restrict__ wdT, const __bf16* __restrict__ sdT,
             const int* __restrict__ counts, const int* __restrict__ offs,
             const int* __restrict__ hdr, const int* __restrict__ dn_tab,
             __bf16* __restrict__ eo, float* __restrict__ out,
             float* __restrict__ sout2)
{
  const int nwg = hdr[1];
  const int orig = blockIdx.x;
  if (orig >= nwg) return;
  const int qq = nwg >> 3, r8 = nwg & 7, xcd = orig & 7;
  const int wgid = (xcd < r8 ? xcd * (qq + 1) : r8 * (qq + 1) + (xcd - r8) * qq)
                   + (orig >> 3);
  const int ent = dn_tab[wgid];
  const int e = ent >> 16, rt = (ent >> 8) & 255, nt = ent & 255;
  const bool SH = (e >= EE);
  const int kh = SH ? (e - EE) : 0;
  const int lda = SH ? IIS : II;            // leading dim of A and B panels
  const int n_rows = SH ? TT : counts[e];
  const int row0 = rt * 256, n0 = nt * 256;
  if (row0 >= n_rows) return;
  const int base = SH ? 0 : offs[e];
  const __bf16* Ain = SH ? (s_buf + (size_t)kh * II)
                         : (a_buf + (size_t)base * II);
  const __bf16* Bd = SH ? (sdT + (size_t)kh * II)
                        : (wdT + (size_t)e * HH * II);

  __shared__ uint4 As[2][2048];    // 256 rows x 8 slots
  __shared__ uint4 Bs[2][2048];    // 256 cols x 8 slots

  const int tid = threadIdx.x;
  const int lane = tid & 63, w = tid >> 6;
  const int wm = w >> 2, wn = w & 3;           // 2x4: per-wave 128 rows x 64 cols
  const int lr = lane & 15, l16 = lane >> 4;

  const __bf16 *pA[4], *pB[4];
#pragma unroll
  for (int i = 0; i < 4; ++i) {
    int s = w * 256 + i * 64 + lane;
    int r = s >> 3, k8 = (s & 7) ^ (r & 7);
    int rr = row0 + r; if (rr >= n_rows) rr = row0;
    pA[i] = Ain + (size_t)rr * lda + k8 * 8;
    pB[i] = Bd + (size_t)(n0 + r) * lda + k8 * 8;
  }

  f32x4 acc[8][4];
  const f32x4 fz = {0.f, 0.f, 0.f, 0.f};
#pragma unroll
  for (int m = 0; m < 8; ++m)
#pragma unroll
    for (int n = 0; n < 4; ++n) acc[m][n] = fz;

#define DN_STAGE(b, k0)                                           \
  {                                                               \
    _Pragma("unroll")                                             \
    for (int i = 0; i < 4; ++i) {                                 \
      gl_lds16(pA[i] + (k0), &As[b][w * 256 + i * 64]);           \
      gl_lds16(pB[i] + (k0), &Bs[b][w * 256 + i * 64]);           \
    }                                                             \
  }

  const int NTS = II >> 6;    // 22 steps for ALL blocks (uniform duration)
  DN_STAGE(0, 0);
  int cur = 0;
  for (int t = 0; t < NTS; ++t) {
    if (t + 1 < NTS) {
      DN_STAGE(cur ^ 1, (t + 1) * 64);
      asm volatile("s_waitcnt vmcnt(8)" ::: "memory");
    } else {
      asm volatile("s_waitcnt vmcnt(0)" ::: "memory");
    }
    __builtin_amdgcn_s_barrier();
#pragma unroll
    for (int ks = 0; ks < 2; ++ks) {
      const int k8r = ks * 4 + l16;
      bf16x8 af[8], bb[4];
#pragma unroll
      for (int m = 0; m < 8; ++m) {
        int rw = wm * 128 + m * 16 + lr;
        af[m] = *reinterpret_cast<const bf16x8*>(
            &As[cur][rw * 8 + (k8r ^ (rw & 7))]);
      }
#pragma unroll
      for (int n = 0; n < 4; ++n) {
        int cn = wn * 64 + n * 16 + lr;
        bb[n] = *reinterpret_cast<const bf16x8*>(
            &Bs[cur][cn * 8 + (k8r ^ (cn & 7))]);
      }
#pragma unroll
      for (int m = 0; m < 8; ++m)
#pragma unroll
        for (int n = 0; n < 4; ++n)
          acc[m][n] = mfma16(af[m], bb[n], acc[m][n]);
    }
    __builtin_amdgcn_s_barrier();
    cur ^= 1;
  }
  float* outSH = kh ? sout2 : out;
#pragma unroll
  for (int m = 0; m < 8; ++m)
#pragma unroll
    for (int n = 0; n < 4; ++n)
#pragma unroll
      for (int q = 0; q < 4; ++q) {
        int rloc = wm * 128 + m * 16 + l16 * 4 + q;
        int cloc = wn * 64 + n * 16 + lr;
        if (SH) {
          outSH[(size_t)(row0 + rloc) * HH + (n0 + cloc)] = acc[m][n][q];
        } else if (row0 + rloc < n_rows) {
          eo[(size_t)(base + row0 + rloc) * HH + (n0 + cloc)] = (__bf16)acc[m][n][q];
        }
      }
#undef DN_STAGE
}

// ---- weighted combine: out = out + sout2 + sum_j w_j * eo[row_j] ----
__global__ __launch_bounds__(256)
void k_combine(const __bf16* __restrict__ eo, const int* __restrict__ row_of,
               const float* __restrict__ wvec, const float* __restrict__ sout2,
               float* __restrict__ out)
{
  const int t = blockIdx.x, tid = threadIdx.x;
  const int h0 = tid * 8;
  float acc[8];
  float4* op = reinterpret_cast<float4*>(out + (size_t)t * HH + h0);
  const float4* sp = reinterpret_cast<const float4*>(sout2 + (size_t)t * HH + h0);
  float4 o0 = op[0], o1 = op[1];
  float4 s0 = sp[0], s1 = sp[1];
  acc[0] = o0.x + s0.x; acc[1] = o0.y + s0.y;
  acc[2] = o0.z + s0.z; acc[3] = o0.w + s0.w;
  acc[4] = o1.x + s1.x; acc[5] = o1.y + s1.y;
  acc[6] = o1.z + s1.z; acc[7] = o1.w + s1.w;
#pragma unroll
  for (int j = 0; j < 4; ++j) {
    int r = row_of[t * 4 + j];
    float wj = wvec[t * 4 + j];
    uint4 v = *reinterpret_cast<const uint4*>(eo + (size_t)r * HH + h0);
    unsigned int ws4[4] = {v.x, v.y, v.z, v.w};
#pragma unroll
    for (int q = 0; q < 4; ++q) {
      acc[q * 2 + 0] += wj * bf2f((unsigned short)(ws4[q] & 0xffffu));
      acc[q * 2 + 1] += wj * bf2f((unsigned short)(ws4[q] >> 16));
    }
  }
  o0.x = acc[0]; o0.y = acc[1]; o0.z = acc[2]; o0.w = acc[3];
  o1.x = acc[4]; o1.y = acc[5]; o1.z = acc[6]; o1.w = acc[7];
  op[0] = o0; op[1] = o1;
}

extern "C" void kernel_launch(void* const* d_in, const int* in_sizes, int n_in,
                              void* d_out, int out_size, void* d_ws, size_t ws_size,
                              hipStream_t stream) {
  const float* x  = (const float*)d_in[0];
  const float* gw = (const float*)d_in[1];
  const float* gb = (const float*)d_in[2];
  const float* wg = (const float*)d_in[3];
  const float* wu = (const float*)d_in[4];
  const float* wd = (const float*)d_in[5];
  const float* sg = (const float*)d_in[6];
  const float* su = (const float*)d_in[7];
  const float* sd = (const float*)d_in[8];
  float* out = (float*)d_out;

  char* ws = (char*)d_ws;
  size_t off = 0;
  auto carve = [&](size_t bytes) {
    off = (off + 255) & ~(size_t)255;
    void* p = (void*)(ws + off);
    off += bytes;
    return p;
  };
  int*    topk_idx = (int*)carve((size_t)TT * KK * 4);
  float*  wvec     = (float*)carve((size_t)TT * KK * 4);
  int*    counts   = (int*)carve(EE * 4);
  int*    offs     = (int*)carve(EE * 4);
  int*    list     = (int*)carve((size_t)EE * TT * 4);
  int*    row_of   = (int*)carve((size_t)TT * KK * 4);
  int*    hdr      = (int*)carve(64);
  int*    gu_tab   = (int*)carve(GU_MAXT * 4);
  int*    dn_tab   = (int*)carve(DN_MAXT * 4);
  __bf16* xb       = (__bf16*)carve((size_t)TT * HH * 2);
  __bf16* a_buf    = (__bf16*)carve((size_t)TT * KK * II * 2);
  __bf16* s_buf    = (__bf16*)carve((size_t)TT * IIS * 2);
  __bf16* eo       = (__bf16*)carve((size_t)TT * KK * HH * 2);
  float*  sout2    = (float*)carve((size_t)TT * HH * 4);
  __bf16* wgT = (__bf16*)carve((size_t)EE * II * HH * 2);
  __bf16* wuT = (__bf16*)carve((size_t)EE * II * HH * 2);
  __bf16* wdT = (__bf16*)carve((size_t)EE * HH * II * 2);
  __bf16* sgT = (__bf16*)carve((size_t)IIS * HH * 2);
  __bf16* suT = (__bf16*)carve((size_t)IIS * HH * 2);
  __bf16* sdT = (__bf16*)carve((size_t)HH * IIS * 2);
  const bool big = (off <= ws_size);

  // fused routing + pipelined gate/up/shared-gu weight transpose (8 tiles/blk)
  const int rt_blocks = big ? (TT + TR_BLK8) : TT;
  k_route_tr<<<rt_blocks, 256, 0, stream>>>(
      x, gw, gb, topk_idx, wvec, xb, wg, wgT, wu, wuT, sg, sgT, su, suT);
  k_lists<<<1, 1024, 0, stream>>>(topk_idx, counts, offs, list, row_of,
                                  hdr, gu_tab, dn_tab);

  if (big) {
    // fused: gate/up GEMM (counted-vmcnt) + pipelined wd/sd transpose tail
    k_gu_trd<<<GU_MAXT + TRD_BLK8, 512, 0, stream>>>(
        xb, wgT, wuT, sgT, suT, counts, offs, list, hdr, gu_tab,
        a_buf, s_buf, wd, wdT, sd, sdT);
    // down GEMM 256x256, uniform 22-step blocks (shared expert K-split)
    k_down5<<<DN_MAXT, 512, 0, stream>>>(
        a_buf, s_buf, wdT, sdT, counts, offs, hdr, dn_tab, eo, out, sout2);
  }
  k_combine<<<TT, 256, 0, stream>>>(eo, row_of, wvec, sout2, out);
}

// Round 21
// 354.063 us; speedup vs baseline: 1.0096x; 1.0096x over previous
//
#include <hip/hip_runtime.h>
#include <hip/hip_bf16.h>

#define TT 1024
#define HH 2048
#define EE 16
#define KK 4
#define II 1408
#define IIS 2816
#define GU_MAXT 448
#define DN_MAXT 320
#define TRD_WD (32 * 22 * 16)   // wd transpose tiles
#define TRD_SD (32 * 44)        // sd transpose tiles
#define TRD_BLK ((TRD_WD + TRD_SD) / 4)   // 3168 trailing blocks, 4 tiles each
// route+tr fused dispatch tile counts
#define TR_GU (22 * 32 * 32)    // wg+wu tiles (22528)
#define TR_SGU (44 * 32 * 2)    // sg+su tiles (2816)
#define TR_BLK4 ((TR_GU + TR_SGU) / 4)   // 6336 transpose blocks, 4 tiles each

typedef __bf16 bf16x8 __attribute__((ext_vector_type(8)));
typedef float f32x4 __attribute__((ext_vector_type(4)));

__device__ __forceinline__ f32x4 mfma16(bf16x8 a, bf16x8 b, f32x4 c) {
  return __builtin_amdgcn_mfma_f32_16x16x32_bf16(a, b, c, 0, 0, 0);
}

__device__ __forceinline__ void gl_lds16(const void* g, void* l) {
  __builtin_amdgcn_global_load_lds(
      (const __attribute__((address_space(1))) void*)g,
      (__attribute__((address_space(3))) void*)l, 16, 0, 0);
}

__device__ __forceinline__ unsigned int pk2(float a, float b) {
  unsigned short lo = __builtin_bit_cast(unsigned short, (__bf16)a);
  unsigned short hi = __builtin_bit_cast(unsigned short, (__bf16)b);
  return (unsigned int)lo | ((unsigned int)hi << 16);
}

__device__ __forceinline__ uint4 pack8(const float* f) {
  uint4 r;
  r.x = pk2(f[0], f[1]);
  r.y = pk2(f[2], f[3]);
  r.z = pk2(f[4], f[5]);
  r.w = pk2(f[6], f[7]);
  return r;
}

__device__ __forceinline__ float bf2f(unsigned short u) {
  return __builtin_bit_cast(float, (unsigned int)u << 16);
}

// ------- fused: routing (blocks < TT) + PIPELINED wg/wu/sg/su transpose -----
__global__ __launch_bounds__(256)
void k_route_tr(const float* __restrict__ x, const float* __restrict__ gw,
                const float* __restrict__ gb,
                int* __restrict__ topk_idx, float* __restrict__ wvec,
                __bf16* __restrict__ xb,
                const float* __restrict__ wg, __bf16* __restrict__ wgT,
                const float* __restrict__ wu, __bf16* __restrict__ wuT,
                const float* __restrict__ sg, __bf16* __restrict__ sgT,
                const float* __restrict__ su, __bf16* __restrict__ suT)
{
  __shared__ float tsm[64][65];
  const int bid = blockIdx.x;
  const int tid = threadIdx.x;
  if (bid >= TT) {
    const int tb = bid - TT;
    const int t0 = tb * 4;
    const float* src; __bf16* dst; int C_, zb;
    int xs[4], ys[4];
    if (t0 < TR_GU) {
      int z = t0 / (22 * 32);
      C_ = II;
      if (z < EE) { src = wg; dst = wgT; zb = z; }
      else        { src = wu; dst = wuT; zb = z - EE; }
#pragma unroll
      for (int j = 0; j < 4; ++j) {
        int tt = t0 + j;
        xs[j] = tt % 22; ys[j] = (tt / 22) & 31;
      }
    } else {
      int t2 = t0 - TR_GU;
      int z = t2 / (44 * 32);
      C_ = IIS;
      if (z == 0) { src = sg; dst = sgT; } else { src = su; dst = suT; }
      zb = 0;
#pragma unroll
      for (int j = 0; j < 4; ++j) {
        int tt = t2 + j;
        xs[j] = tt % 44; ys[j] = (tt / 44) & 31;
      }
    }
    const size_t mb = (size_t)zb * HH * C_;
    const int r_ld = tid >> 4, q_ld = tid & 15;
    const int n_st = tid >> 3, q8_st = tid & 7;

    float4 A[4], B[4];
#define RT_LOAD(V, j)                                                        \
    { _Pragma("unroll")                                                      \
      for (int it = 0; it < 4; ++it)                                         \
        V[it] = *reinterpret_cast<const float4*>(src + mb                    \
            + (size_t)(ys[j] * 64 + it * 16 + r_ld) * C_                     \
            + xs[j] * 64 + q_ld * 4); }

    RT_LOAD(A, 0)
#pragma unroll
    for (int j = 0; j < 4; ++j) {
#pragma unroll
      for (int it = 0; it < 4; ++it) {
        int r = it * 16 + r_ld;
        tsm[r][q_ld * 4 + 0] = A[it].x; tsm[r][q_ld * 4 + 1] = A[it].y;
        tsm[r][q_ld * 4 + 2] = A[it].z; tsm[r][q_ld * 4 + 3] = A[it].w;
      }
      if (j < 3) { RT_LOAD(B, j + 1) }     // next tile's loads in flight
      __syncthreads();
#pragma unroll
      for (int it = 0; it < 2; ++it) {
        int n = it * 32 + n_st;
        float f[8];
#pragma unroll
        for (int jj = 0; jj < 8; ++jj) f[jj] = tsm[q8_st * 8 + jj][n];
        *reinterpret_cast<uint4*>(dst + mb
            + (size_t)(xs[j] * 64 + n) * HH + ys[j] * 64 + q8_st * 8) = pack8(f);
      }
      __syncthreads();
      if (j < 3) {
#pragma unroll
        for (int it = 0; it < 4; ++it) A[it] = B[it];
      }
    }
#undef RT_LOAD
    return;
  }
  // ---------------- routing body ----------------
  const int t = bid;
  float a[EE];
#pragma unroll
  for (int e = 0; e < EE; ++e) a[e] = 0.f;
  for (int h = tid; h < HH; h += 256) {
    float xv = x[(size_t)t * HH + h];
    xb[(size_t)t * HH + h] = (__bf16)xv;
#pragma unroll
    for (int e = 0; e < EE; ++e) a[e] += xv * gw[e * HH + h];
  }
  const int lane = tid & 63, wv = tid >> 6;
#pragma unroll
  for (int e = 0; e < EE; ++e) {
    float v = a[e];
#pragma unroll
    for (int off = 32; off > 0; off >>= 1) v += __shfl_xor(v, off);
    if (lane == 0) tsm[wv][e] = v;
  }
  __syncthreads();
  if (tid == 0) {
    float sc[EE], sb[EE];
    for (int e = 0; e < EE; ++e) {
      float lg = tsm[0][e] + tsm[1][e] + tsm[2][e] + tsm[3][e];
      sc[e] = 1.f / (1.f + expf(-lg));
      sb[e] = sc[e] + gb[e];
    }
    float gsc[4];
    for (int g = 0; g < 4; ++g) {
      float m1 = -1e30f, m2 = -1e30f;
      for (int j = 0; j < 4; ++j) {
        float v = sb[g * 4 + j];
        if (v > m1) { m2 = m1; m1 = v; } else if (v > m2) { m2 = v; }
      }
      gsc[g] = m1 + m2;
    }
    int g1 = 0; float b1 = gsc[0];
    for (int g = 1; g < 4; ++g) if (gsc[g] > b1) { b1 = gsc[g]; g1 = g; }
    int g2 = 0; float b2 = -1e30f;
    for (int g = 0; g < 4; ++g) if (g != g1 && gsc[g] > b2) { b2 = gsc[g]; g2 = g; }
    bool used[EE];
    for (int e = 0; e < EE; ++e) used[e] = !(((e >> 2) == g1) || ((e >> 2) == g2));
    int sel[KK]; float sw[KK]; float ssum = 0.f;
    for (int j = 0; j < KK; ++j) {
      float best = -1e30f; int bi = 0;
      for (int e = 0; e < EE; ++e)
        if (!used[e] && sb[e] > best) { best = sb[e]; bi = e; }
      used[bi] = true; sel[j] = bi; sw[j] = sc[bi]; ssum += sc[bi];
    }
    float s = 2.5f / (ssum + 1e-20f);
    for (int j = 0; j < KK; ++j) {
      topk_idx[t * KK + j] = sel[j];
      wvec[t * KK + j] = sw[j] * s;
    }
  }
}

// ------ deterministic expert lists + compacted tile tables -------
// gu: BM=256 x BN=128, order (e, nt, rt)
// dn: BM=256 x BN=256, order (e, rt, nt); SHARED expert split into two
//     K-halves (e = EE -> k half 0, e = EE+1 -> k half 1), 22 steps each.
__global__ __launch_bounds__(1024)
void k_lists(const int* __restrict__ topk_idx,
             int* __restrict__ counts, int* __restrict__ offs,
             int* __restrict__ list, int* __restrict__ row_of,
             int* __restrict__ hdr, int* __restrict__ gu_tab,
             int* __restrict__ dn_tab)
{
  const int t = threadIdx.x;
  const int lane = t & 63, wv = t >> 6;
  const int e0 = topk_idx[t * 4 + 0], e1 = topk_idx[t * 4 + 1],
            e2 = topk_idx[t * 4 + 2], e3 = topk_idx[t * 4 + 3];
  __shared__ int wtot[16];
  __shared__ int cnt[EE];
  __shared__ int offsh[EE + 1];
  __shared__ int rtn[EE], gpre[EE + 1], dpre[EE + 1];
  int p0 = 0, p1 = 0, p2 = 0, p3 = 0;
  for (int e = 0; e < EE; ++e) {
    bool f = (e0 == e) || (e1 == e) || (e2 == e) || (e3 == e);
    unsigned long long b = __ballot(f);
    if (lane == 0) wtot[wv] = __popcll(b);
    __syncthreads();
    int wo = 0;
    for (int w2 = 0; w2 < wv; ++w2) wo += wtot[w2];
    if (f) {
      int pos = wo + __popcll(b & ((1ull << lane) - 1ull));
      list[e * TT + pos] = t;
      if (e0 == e) p0 = pos; else if (e1 == e) p1 = pos;
      else if (e2 == e) p2 = pos; else p3 = pos;
    }
    if (t == 0) {
      int tot = 0;
      for (int w2 = 0; w2 < 16; ++w2) tot += wtot[w2];
      cnt[e] = tot;
    }
    __syncthreads();
  }
  if (t == 0) {
    offsh[0] = 0;
    for (int e = 0; e < EE; ++e) offsh[e + 1] = offsh[e] + cnt[e];
    for (int e = 0; e < EE; ++e) { counts[e] = cnt[e]; offs[e] = offsh[e]; }
    gpre[0] = 0; dpre[0] = 0;
    for (int e = 0; e < EE; ++e) {
      int rr = (cnt[e] + 255) >> 8;           // ceil(cnt/256)
      rtn[e] = rr;
      gpre[e + 1] = gpre[e] + rr * (II / 128);
      dpre[e + 1] = dpre[e] + rr * (HH / 256);
    }
    hdr[0] = gpre[EE] + 4 * (IIS / 128);      // gu shared: 4 row-tiles of 256
    hdr[1] = dpre[EE] + 2 * 4 * (HH / 256);   // dn shared: 2 K-halves x 4 rt x 8 nt
  }
  __syncthreads();
  row_of[t * 4 + 0] = offsh[e0] + p0;
  row_of[t * 4 + 1] = offsh[e1] + p1;
  row_of[t * 4 + 2] = offsh[e2] + p2;
  row_of[t * 4 + 3] = offsh[e3] + p3;
  if (t < EE) {
    int rr = rtn[t];
    int p = gpre[t];
    for (int nt = 0; nt < II / 128; ++nt)
      for (int rt = 0; rt < rr; ++rt) gu_tab[p++] = (t << 16) | (rt << 8) | nt;
    p = dpre[t];
    for (int rt = 0; rt < rr; ++rt)
      for (int nt = 0; nt < HH / 256; ++nt) dn_tab[p++] = (t << 16) | (rt << 8) | nt;
  } else if (t == EE) {
    int p = gpre[EE];
    for (int nt = 0; nt < IIS / 128; ++nt)
      for (int rt = 0; rt < 4; ++rt) gu_tab[p++] = (EE << 16) | (rt << 8) | nt;
    p = dpre[EE];
    for (int kh = 0; kh < 2; ++kh)
      for (int rt = 0; rt < 4; ++rt)
        for (int nt = 0; nt < HH / 256; ++nt)
          dn_tab[p++] = ((EE + kh) << 16) | (rt << 8) | nt;
  }
}

// ---- fused: gate/up GEMM (BM=256, dbuf, counted-vmcnt) + wd/sd transpose ----
struct GU_SM {
  uint4 As[2][2048];
  uint4 Bgs[2][1024];
  uint4 Bus[2][1024];
  int toks[256];
};
union FSM { GU_SM g; float t[64][65]; };

__global__ __launch_bounds__(512)
void k_gu_trd(const __bf16* __restrict__ xb,
              const __bf16* __restrict__ wgT, const __bf16* __restrict__ wuT,
              const __bf16* __restrict__ sgT, const __bf16* __restrict__ suT,
              const int* __restrict__ counts, const int* __restrict__ offs,
              const int* __restrict__ list, const int* __restrict__ hdr,
              const int* __restrict__ gu_tab,
              __bf16* __restrict__ a_buf, __bf16* __restrict__ s_buf,
              const float* __restrict__ wd, __bf16* __restrict__ wdT,
              const float* __restrict__ sd, __bf16* __restrict__ sdT)
{
  __shared__ FSM sm;
  const int bid = blockIdx.x;
  if (bid >= GU_MAXT) {
    // ---- pipelined trailing transpose: 4 homogeneous tiles per block ----
    const int tb = bid - GU_MAXT;
    const int tid2 = threadIdx.x;
    const bool isWd = (tb * 4) < TRD_WD;       // TRD_WD % 4 == 0
    const float* src = isWd ? wd : sd;
    __bf16* dst = isWd ? wdT : sdT;
    const int R = isWd ? II : IIS;
    const int t0 = isWd ? tb * 4 : tb * 4 - TRD_WD;
    const int r_ld = tid2 >> 4, q_ld = tid2 & 15;   // rows r_ld, r_ld+32
    const int n_st = tid2 >> 3, q8_st = tid2 & 7;

    int xs[4], ys[4], zs[4];
#pragma unroll
    for (int j = 0; j < 4; ++j) {
      int tile = t0 + j;
      xs[j] = tile & 31;
      ys[j] = isWd ? ((tile >> 5) % 22) : (tile >> 5);
      zs[j] = isWd ? (tile / (32 * 22)) : 0;
    }

    float4 A0, A1, B0, B1;
#define TR_LOAD(Va, Vb, j)                                                   \
    { const float* p_ = src + (size_t)zs[j] * R * HH                         \
          + (size_t)(ys[j] * 64 + r_ld) * HH + xs[j] * 64 + q_ld * 4;        \
      Va = *reinterpret_cast<const float4*>(p_);                             \
      Vb = *reinterpret_cast<const float4*>(p_ + (size_t)32 * HH); }

    TR_LOAD(A0, A1, 0)
#pragma unroll
    for (int j = 0; j < 4; ++j) {
      sm.t[r_ld][q_ld * 4 + 0] = A0.x; sm.t[r_ld][q_ld * 4 + 1] = A0.y;
      sm.t[r_ld][q_ld * 4 + 2] = A0.z; sm.t[r_ld][q_ld * 4 + 3] = A0.w;
      sm.t[r_ld + 32][q_ld * 4 + 0] = A1.x; sm.t[r_ld + 32][q_ld * 4 + 1] = A1.y;
      sm.t[r_ld + 32][q_ld * 4 + 2] = A1.z; sm.t[r_ld + 32][q_ld * 4 + 3] = A1.w;
      if (j < 3) { TR_LOAD(B0, B1, j + 1) }    // next tile in flight
      __syncthreads();
      {
        float f[8];
#pragma unroll
        for (int jj = 0; jj < 8; ++jj) f[jj] = sm.t[q8_st * 8 + jj][n_st];
        *reinterpret_cast<uint4*>(dst + (size_t)zs[j] * R * HH
            + (size_t)(xs[j] * 64 + n_st) * R + ys[j] * 64 + q8_st * 8) = pack8(f);
      }
      __syncthreads();
      if (j < 3) { A0 = B0; A1 = B1; }
    }
#undef TR_LOAD
    return;
  }
  const int nwg = hdr[0];
  if (bid >= nwg) return;
  const int qq = nwg >> 3, r8 = nwg & 7, xcd = bid & 7;
  const int wgid = (xcd < r8 ? xcd * (qq + 1) : r8 * (qq + 1) + (xcd - r8) * qq)
                   + (bid >> 3);
  const int ent = gu_tab[wgid];
  const int e = ent >> 16, rt = (ent >> 8) & 255, nt = ent & 255;
  const bool SH = (e == EE);
  const int Nt = SH ? IIS : II;
  const int n0 = nt * 128, row0 = rt * 256;
  const int n_rows = SH ? TT : counts[e];
  if (row0 >= n_rows) return;
  const int base = SH ? 0 : offs[e];
  const __bf16* Bg = SH ? sgT : wgT + (size_t)e * II * HH;
  const __bf16* Bu = SH ? suT : wuT + (size_t)e * II * HH;
  __bf16* outp = SH ? s_buf : a_buf;

  const int tid = threadIdx.x;
  const int lane = tid & 63, w = tid >> 6;
  if (tid < 256) {
    int rr = row0 + tid;
    sm.g.toks[tid] = SH ? rr : list[e * TT + (rr < n_rows ? rr : row0)];
  }
  __syncthreads();

  const __bf16 *pA[4], *pBg[2], *pBu[2];
#pragma unroll
  for (int i = 0; i < 4; ++i) {
    int s = w * 256 + i * 64 + lane;
    int r = s >> 3, k8 = (s & 7) ^ (r & 7);
    pA[i] = xb + (size_t)sm.g.toks[r] * HH + k8 * 8;
  }
#pragma unroll
  for (int i = 0; i < 2; ++i) {
    int s = w * 128 + i * 64 + lane;
    int r = s >> 3, k8 = (s & 7) ^ (r & 7);
    pBg[i] = Bg + (size_t)(n0 + r) * HH + k8 * 8;
    pBu[i] = Bu + (size_t)(n0 + r) * HH + k8 * 8;
  }

  f32x4 accg[4][4], accu[4][4];
  const f32x4 fz = {0.f, 0.f, 0.f, 0.f};
#pragma unroll
  for (int m = 0; m < 4; ++m)
#pragma unroll
    for (int n = 0; n < 4; ++n) { accg[m][n] = fz; accu[m][n] = fz; }

  const int wm = w >> 1, wn = w & 1;
  const int lr = lane & 15, l16 = lane >> 4;

#define GU_STAGE(b, k0)                                            \
  {                                                                \
    _Pragma("unroll")                                              \
    for (int i = 0; i < 4; ++i)                                    \
      gl_lds16(pA[i] + (k0), &sm.g.As[b][w * 256 + i * 64]);       \
    _Pragma("unroll")                                              \
    for (int i = 0; i < 2; ++i) {                                  \
      gl_lds16(pBg[i] + (k0), &sm.g.Bgs[b][w * 128 + i * 64]);     \
      gl_lds16(pBu[i] + (k0), &sm.g.Bus[b][w * 128 + i * 64]);     \
    }                                                              \
  }

  GU_STAGE(0, 0);
  int cur = 0;
  for (int t = 0; t < HH / 64; ++t) {
    if (t + 1 < HH / 64) {
      GU_STAGE(cur ^ 1, (t + 1) * 64);
      asm volatile("s_waitcnt vmcnt(8)" ::: "memory");
    } else {
      asm volatile("s_waitcnt vmcnt(0)" ::: "memory");
    }
    __builtin_amdgcn_s_barrier();
#pragma unroll
    for (int ks = 0; ks < 2; ++ks) {
      const int k8r = ks * 4 + l16;
      bf16x8 af[4], bg[4], bu[4];
#pragma unroll
      for (int m = 0; m < 4; ++m) {
        int rw = wm * 64 + m * 16 + lr;
        af[m] = *reinterpret_cast<const bf16x8*>(
            &sm.g.As[cur][rw * 8 + (k8r ^ (rw & 7))]);
      }
#pragma unroll
      for (int n = 0; n < 4; ++n) {
        int cn = wn * 64 + n * 16 + lr;
        bg[n] = *reinterpret_cast<const bf16x8*>(
            &sm.g.Bgs[cur][cn * 8 + (k8r ^ (cn & 7))]);
        bu[n] = *reinterpret_cast<const bf16x8*>(
            &sm.g.Bus[cur][cn * 8 + (k8r ^ (cn & 7))]);
      }
#pragma unroll
      for (int m = 0; m < 4; ++m)
#pragma unroll
        for (int n = 0; n < 4; ++n) {
          accg[m][n] = mfma16(af[m], bg[n], accg[m][n]);
          accu[m][n] = mfma16(af[m], bu[n], accu[m][n]);
        }
    }
    __builtin_amdgcn_s_barrier();
    cur ^= 1;
  }
#pragma unroll
  for (int m = 0; m < 4; ++m)
#pragma unroll
    for (int n = 0; n < 4; ++n)
#pragma unroll
      for (int q = 0; q < 4; ++q) {
        int rloc = wm * 64 + m * 16 + l16 * 4 + q;
        if (row0 + rloc >= n_rows) continue;
        int cloc = wn * 64 + n * 16 + lr;
        float g = accg[m][n][q], u = accu[m][n][q];
        float sv = g / (1.f + __expf(-g)) * u;
        outp[(size_t)(base + row0 + rloc) * Nt + (n0 + cloc)] = (__bf16)sv;
      }
#undef GU_STAGE
}

// ---- down GEMM: BM=256, BN=256, BK=64, counted-vmcnt; shared K-split ----
// Every block runs exactly II/64 = 22 K-steps. Shared expert: e==EE -> K rows
// [0,1408) writing out; e==EE+1 -> K rows [1408,2816) writing sout2 (fp32
// partial, summed in k_combine).
__global__ __launch_bounds__(512)
void k_down5(const __bf16* __restrict__ a_buf, const __bf16* __restrict__ s_buf,
             const __bf16* __restrict__ wdT, const __bf16* __restrict__ sdT,
             const int* __restrict__ counts, const int* __restrict__ offs,
             const int* __restrict__ hdr, const int* __restrict__ dn_tab,
             __bf16* __restrict__ eo, float* __restrict__ out,
             float* __restrict__ sout2)
{
  const int nwg = hdr[1];
  const int orig = blockIdx.x;
  if (orig >= nwg) return;
  const int qq = nwg >> 3, r8 = nwg & 7, xcd = orig & 7;
  const int wgid = (xcd < r8 ? xcd * (qq + 1) : r8 * (qq + 1) + (xcd - r8) * qq)
                   + (orig >> 3);
  const int ent = dn_tab[wgid];
  const int e = ent >> 16, rt = (ent >> 8) & 255, nt = ent & 255;
  const bool SH = (e >= EE);
  const int kh = SH ? (e - EE) : 0;
  const int lda = SH ? IIS : II;            // leading dim of A and B panels
  const int n_rows = SH ? TT : counts[e];
  const int row0 = rt * 256, n0 = nt * 256;
  if (row0 >= n_rows) return;
  const int base = SH ? 0 : offs[e];
  const __bf16* Ain = SH ? (s_buf + (size_t)kh * II)
                         : (a_buf + (size_t)base * II);
  const __bf16* Bd = SH ? (sdT + (size_t)kh * II)
                        : (wdT + (size_t)e * HH * II);

  __shared__ uint4 As[2][2048];    // 256 rows x 8 slots
  __shared__ uint4 Bs[2][2048];    // 256 cols x 8 slots

  const int tid = threadIdx.x;
  const int lane = tid & 63, w = tid >> 6;
  const int wm = w >> 2, wn = w & 3;           // 2x4: per-wave 128 rows x 64 cols
  const int lr = lane & 15, l16 = lane >> 4;

  const __bf16 *pA[4], *pB[4];
#pragma unroll
  for (int i = 0; i < 4; ++i) {
    int s = w * 256 + i * 64 + lane;
    int r = s >> 3, k8 = (s & 7) ^ (r & 7);
    int rr = row0 + r; if (rr >= n_rows) rr = row0;
    pA[i] = Ain + (size_t)rr * lda + k8 * 8;
    pB[i] = Bd + (size_t)(n0 + r) * lda + k8 * 8;
  }

  f32x4 acc[8][4];
  const f32x4 fz = {0.f, 0.f, 0.f, 0.f};
#pragma unroll
  for (int m = 0; m < 8; ++m)
#pragma unroll
    for (int n = 0; n < 4; ++n) acc[m][n] = fz;

#define DN_STAGE(b, k0)                                           \
  {                                                               \
    _Pragma("unroll")                                             \
    for (int i = 0; i < 4; ++i) {                                 \
      gl_lds16(pA[i] + (k0), &As[b][w * 256 + i * 64]);           \
      gl_lds16(pB[i] + (k0), &Bs[b][w * 256 + i * 64]);           \
    }                                                             \
  }

  const int NTS = II >> 6;    // 22 steps for ALL blocks (uniform duration)
  DN_STAGE(0, 0);
  int cur = 0;
  for (int t = 0; t < NTS; ++t) {
    if (t + 1 < NTS) {
      DN_STAGE(cur ^ 1, (t + 1) * 64);
      asm volatile("s_waitcnt vmcnt(8)" ::: "memory");
    } else {
      asm volatile("s_waitcnt vmcnt(0)" ::: "memory");
    }
    __builtin_amdgcn_s_barrier();
#pragma unroll
    for (int ks = 0; ks < 2; ++ks) {
      const int k8r = ks * 4 + l16;
      bf16x8 af[8], bb[4];
#pragma unroll
      for (int m = 0; m < 8; ++m) {
        int rw = wm * 128 + m * 16 + lr;
        af[m] = *reinterpret_cast<const bf16x8*>(
            &As[cur][rw * 8 + (k8r ^ (rw & 7))]);
      }
#pragma unroll
      for (int n = 0; n < 4; ++n) {
        int cn = wn * 64 + n * 16 + lr;
        bb[n] = *reinterpret_cast<const bf16x8*>(
            &Bs[cur][cn * 8 + (k8r ^ (cn & 7))]);
      }
#pragma unroll
      for (int m = 0; m < 8; ++m)
#pragma unroll
        for (int n = 0; n < 4; ++n)
          acc[m][n] = mfma16(af[m], bb[n], acc[m][n]);
    }
    __builtin_amdgcn_s_barrier();
    cur ^= 1;
  }
  float* outSH = kh ? sout2 : out;
#pragma unroll
  for (int m = 0; m < 8; ++m)
#pragma unroll
    for (int n = 0; n < 4; ++n)
#pragma unroll
      for (int q = 0; q < 4; ++q) {
        int rloc = wm * 128 + m * 16 + l16 * 4 + q;
        int cloc = wn * 64 + n * 16 + lr;
        if (SH) {
          outSH[(size_t)(row0 + rloc) * HH + (n0 + cloc)] = acc[m][n][q];
        } else if (row0 + rloc < n_rows) {
          eo[(size_t)(base + row0 + rloc) * HH + (n0 + cloc)] = (__bf16)acc[m][n][q];
        }
      }
#undef DN_STAGE
}

// ---- weighted combine: out = out + sout2 + sum_j w_j * eo[row_j] ----
__global__ __launch_bounds__(256)
void k_combine(const __bf16* __restrict__ eo, const int* __restrict__ row_of,
               const float* __restrict__ wvec, const float* __restrict__ sout2,
               float* __restrict__ out)
{
  const int t = blockIdx.x, tid = threadIdx.x;
  const int h0 = tid * 8;
  float acc[8];
  float4* op = reinterpret_cast<float4*>(out + (size_t)t * HH + h0);
  const float4* sp = reinterpret_cast<const float4*>(sout2 + (size_t)t * HH + h0);
  float4 o0 = op[0], o1 = op[1];
  float4 s0 = sp[0], s1 = sp[1];
  acc[0] = o0.x + s0.x; acc[1] = o0.y + s0.y;
  acc[2] = o0.z + s0.z; acc[3] = o0.w + s0.w;
  acc[4] = o1.x + s1.x; acc[5] = o1.y + s1.y;
  acc[6] = o1.z + s1.z; acc[7] = o1.w + s1.w;
#pragma unroll
  for (int j = 0; j < 4; ++j) {
    int r = row_of[t * 4 + j];
    float wj = wvec[t * 4 + j];
    uint4 v = *reinterpret_cast<const uint4*>(eo + (size_t)r * HH + h0);
    unsigned int ws4[4] = {v.x, v.y, v.z, v.w};
#pragma unroll
    for (int q = 0; q < 4; ++q) {
      acc[q * 2 + 0] += wj * bf2f((unsigned short)(ws4[q] & 0xffffu));
      acc[q * 2 + 1] += wj * bf2f((unsigned short)(ws4[q] >> 16));
    }
  }
  o0.x = acc[0]; o0.y = acc[1]; o0.z = acc[2]; o0.w = acc[3];
  o1.x = acc[4]; o1.y = acc[5]; o1.z = acc[6]; o1.w = acc[7];
  op[0] = o0; op[1] = o1;
}

extern "C" void kernel_launch(void* const* d_in, const int* in_sizes, int n_in,
                              void* d_out, int out_size, void* d_ws, size_t ws_size,
                              hipStream_t stream) {
  const float* x  = (const float*)d_in[0];
  const float* gw = (const float*)d_in[1];
  const float* gb = (const float*)d_in[2];
  const float* wg = (const float*)d_in[3];
  const float* wu = (const float*)d_in[4];
  const float* wd = (const float*)d_in[5];
  const float* sg = (const float*)d_in[6];
  const float* su = (const float*)d_in[7];
  const float* sd = (const float*)d_in[8];
  float* out = (float*)d_out;

  char* ws = (char*)d_ws;
  size_t off = 0;
  auto carve = [&](size_t bytes) {
    off = (off + 255) & ~(size_t)255;
    void* p = (void*)(ws + off);
    off += bytes;
    return p;
  };
  int*    topk_idx = (int*)carve((size_t)TT * KK * 4);
  float*  wvec     = (float*)carve((size_t)TT * KK * 4);
  int*    counts   = (int*)carve(EE * 4);
  int*    offs     = (int*)carve(EE * 4);
  int*    list     = (int*)carve((size_t)EE * TT * 4);
  int*    row_of   = (int*)carve((size_t)TT * KK * 4);
  int*    hdr      = (int*)carve(64);
  int*    gu_tab   = (int*)carve(GU_MAXT * 4);
  int*    dn_tab   = (int*)carve(DN_MAXT * 4);
  __bf16* xb       = (__bf16*)carve((size_t)TT * HH * 2);
  __bf16* a_buf    = (__bf16*)carve((size_t)TT * KK * II * 2);
  __bf16* s_buf    = (__bf16*)carve((size_t)TT * IIS * 2);
  __bf16* eo       = (__bf16*)carve((size_t)TT * KK * HH * 2);
  float*  sout2    = (float*)carve((size_t)TT * HH * 4);
  __bf16* wgT = (__bf16*)carve((size_t)EE * II * HH * 2);
  __bf16* wuT = (__bf16*)carve((size_t)EE * II * HH * 2);
  __bf16* wdT = (__bf16*)carve((size_t)EE * HH * II * 2);
  __bf16* sgT = (__bf16*)carve((size_t)IIS * HH * 2);
  __bf16* suT = (__bf16*)carve((size_t)IIS * HH * 2);
  __bf16* sdT = (__bf16*)carve((size_t)HH * IIS * 2);
  const bool big = (off <= ws_size);

  // fused routing + pipelined gate/up/shared-gu weight transpose (4 tiles/blk)
  const int rt_blocks = big ? (TT + TR_BLK4) : TT;
  k_route_tr<<<rt_blocks, 256, 0, stream>>>(
      x, gw, gb, topk_idx, wvec, xb, wg, wgT, wu, wuT, sg, sgT, su, suT);
  k_lists<<<1, 1024, 0, stream>>>(topk_idx, counts, offs, list, row_of,
                                  hdr, gu_tab, dn_tab);

  if (big) {
    // fused: gate/up GEMM (counted-vmcnt) + pipelined wd/sd transpose tail
    k_gu_trd<<<GU_MAXT + TRD_BLK, 512, 0, stream>>>(
        xb, wgT, wuT, sgT, suT, counts, offs, list, hdr, gu_tab,
        a_buf, s_buf, wd, wdT, sd, sdT);
    // down GEMM 256x256, uniform 22-step blocks (shared expert K-split)
    k_down5<<<DN_MAXT, 512, 0, stream>>>(
        a_buf, s_buf, wdT, sdT, counts, offs, hdr, dn_tab, eo, out, sout2);
  }
  k_combine<<<TT, 256, 0, stream>>>(eo, row_of, wvec, sout2, out);
}